// Round 8
// baseline (246.874 us; speedup 1.0000x reference)
//
#include <hip/hip_runtime.h>
#include <math.h>

// ExodusNeuron: per-(b,n) sequential scan over T with spike threshold/reset.
// x: (B=32, T=2048, N=512, 1) fp32; weight: (1,1) fp32; out: (B,T,N,1) fp32.
//
// R7: R6's producer/consumer structure at TWO BLOCKS PER CU.
//   R6 refuted "more producer waves => more BW" (8 waves == 4 waves == ~83us).
//   The serialized per-window cost is the barrier drain: vmcnt(0) before
//   s_barrier joins ALL waves of the block -> whole CU goes memory-silent
//   during the load-latency + store-ack tail of every one of 33 windows.
//   Fix: 512 blocks (2/CU), 32 neurons each. While block A sits in its
//   barrier drain, block B's producers stream -- the two pipelines
//   interleave and keep the CU's memory pipe busy.
//   Block: 320 threads = 1 consumer wave (32 active lanes) + 4 producer
//   waves; each producer stages 16 rows/tile as 8 two-row wave-loads
//   (64 lanes = 2 rows x 32 neurons, 256B contiguous). Tiles 64 steps x
//   32 neurons double-buffered: XBUF+SBUF = 32 KB LDS/block (64 KB/CU).
//
// Numerics MUST match numpy's fp32 rounding exactly (outputs are 0/1 spikes;
// a flipped spike = absmax 1.0): separate rounded mul/add (no FMA), and
// alpha = correctly-rounded float of exp(double(float(-0.05))).
// fire ? __fsub_rn(va,1.0f) : va is bitwise identical to va - spk.
// R0-R6 all passed with absmax == 0.0 — do not change the arithmetic.

constexpr int B_ = 32;
constexpr int T_ = 2048;
constexpr int N_ = 512;
constexpr int TILE = 64;               // time steps per tile
constexpr int NTILE = T_ / TILE;       // 32 tiles
constexpr int NCHUNK = 32;             // neurons per block (R6 had 64)
constexpr int NPROD = 4;               // producer waves
constexpr int RPP = TILE / NPROD;      // 16 rows per producer
constexpr int LPP = RPP / 2;           // 8 two-row wave-loads per producer

__global__ __launch_bounds__(64 * (NPROD + 1), 1)
void exodus_pc2b_kernel(const float* __restrict__ x,
                        const float* __restrict__ wptr,
                        float* __restrict__ out) {
    __shared__ float XBUF[2][TILE * NCHUNK];   // staged input tiles (16 KB)
    __shared__ float SBUF[2][TILE * NCHUNK];   // staged spike tiles (16 KB)

    const int blk  = blockIdx.x;           // 0..511
    const int b    = blk >> 4;             // 0..31  (16 chunks per b)
    const int n0   = (blk & 15) * NCHUNK;  // 0,32,...,480
    const int wave = threadIdx.x >> 6;     // 0..4
    const int lane = threadIdx.x & 63;

    const size_t bbase = (size_t)b * T_ * N_ + (size_t)n0;

    if (wave != 0) {
        // ================= producers =================
        const int p  = wave - 1;            // 0..3
        const int j0 = p * RPP;             // row range [j0, j0+16)
        const int r  = lane >> 5;           // 0/1: row within a 2-row pair
        const int c  = lane & 31;           // neuron column

        // per-lane global address for row (j0 + 2i + r), col c:
        const float* __restrict__ gp = x + bbase + (size_t)(j0 + r) * N_ + c;
        float* __restrict__ op = out + bbase + (size_t)(j0 + r) * N_ + c;
        // per-lane LDS flat offset for the same element:
        const int l0 = j0 * NCHUNK + lane;  // == (j0+r)*32 + c

        // prologue: stage tile 0 (batched: 8 loads, then 8 ds_writes)
        {
            float rg[LPP];
#pragma unroll
            for (int i = 0; i < LPP; ++i) rg[i] = gp[(size_t)(2 * i) * N_];
#pragma unroll
            for (int i = 0; i < LPP; ++i) XBUF[0][l0 + 2 * i * NCHUNK] = rg[i];
        }
        __syncthreads();

        for (int t = 0; t <= NTILE; ++t) {
            if (t + 1 < NTILE) {
                // prefetch tile t+1: 8 batched loads -> 8 ds_writes
                const float* __restrict__ g =
                    gp + (size_t)(t + 1) * TILE * N_;
                const int bb = (t + 1) & 1;
                float rg[LPP];
#pragma unroll
                for (int i = 0; i < LPP; ++i) rg[i] = g[(size_t)(2 * i) * N_];
#pragma unroll
                for (int i = 0; i < LPP; ++i)
                    XBUF[bb][l0 + 2 * i * NCHUNK] = rg[i];
            }
            if (t >= 1) {
                // drain spikes of tile t-1: 8 batched ds_reads -> 8 stores
                float* __restrict__ o = op + (size_t)(t - 1) * TILE * N_;
                const int bb = (t - 1) & 1;
                float s[LPP];
#pragma unroll
                for (int i = 0; i < LPP; ++i)
                    s[i] = SBUF[bb][l0 + 2 * i * NCHUNK];
#pragma unroll
                for (int i = 0; i < LPP; ++i) o[(size_t)(2 * i) * N_] = s[i];
            }
            __syncthreads();
        }
    } else {
        // ================= consumer (32 active lanes) =================
        const float w = wptr[0];
        const float alpha = (float)exp((double)(-1.0f / 20.0f));
        float vsyn = 0.0f, vmem = 0.0f;
        const bool active = (lane < NCHUNK);

        __syncthreads();   // matches producer prologue barrier

        for (int t = 0; t <= NTILE; ++t) {
            if (t < NTILE) {
                const int bb = t & 1;
                if (active) {
#pragma unroll
                    for (int c2 = 0; c2 < TILE / 32; ++c2) {  // 2 chunks of 32
                        float xv[32];
#pragma unroll
                        for (int j = 0; j < 32; ++j)
                            xv[j] = XBUF[bb][(c2 * 32 + j) * NCHUNK + lane];
#pragma unroll
                        for (int j = 0; j < 32; ++j) {
                            const float i_t = __fmul_rn(xv[j], w);
                            vsyn = __fadd_rn(__fmul_rn(alpha, vsyn), i_t);
                            const float va =
                                __fadd_rn(__fmul_rn(alpha, vmem), vsyn);
                            const bool fire = (va >= 1.0f);
                            SBUF[bb][(c2 * 32 + j) * NCHUNK + lane] =
                                fire ? 1.0f : 0.0f;
                            vmem = fire ? __fsub_rn(va, 1.0f) : va;
                        }
                    }
                }
            }
            __syncthreads();
        }
    }
}

extern "C" void kernel_launch(void* const* d_in, const int* in_sizes, int n_in,
                              void* d_out, int out_size, void* d_ws, size_t ws_size,
                              hipStream_t stream) {
    const float* x = (const float*)d_in[0];
    const float* w = (const float*)d_in[1];
    float* out = (float*)d_out;

    dim3 grid(512);               // TWO blocks per CU; 32 sequences per block
    dim3 block(64 * (NPROD + 1)); // 320 threads = 1 consumer + 4 producers
    hipLaunchKernelGGL(exodus_pc2b_kernel, grid, block, 0, stream, x, w, out);
}